// Round 2
// baseline (341.129 us; speedup 1.0000x reference)
//
#include <hip/hip_runtime.h>

// B=1024, S=256, D=128, F=4D=512, H1=256, H2=64.
// Folding: feat@W1 = q@(W1a+W1c) [per-batch bias] + k@(W1b-W1c) + (q*k)@W1d
//   => layer1 = [32 x 256] @ [256 x 256] bf16 MFMA GEMM per s-tile.
// R2: 4 blocks/CU (LDS 35KB), keys prefetch across lgkmcnt-only barriers,
//     GEMM2 full-K on waves 0/1 (no LDS reduction), streamed W1/W2 fragments.

typedef unsigned short u16;
typedef unsigned int u32;
typedef short bf16x8 __attribute__((ext_vector_type(8)));
typedef float f32x4 __attribute__((ext_vector_type(4)));

#define NBATCH 1024
#define SLEN 256
#define DD 128
#define NH1 256
#define NH2 64

// ws layout (bytes) — same as R1
#define WS_WCATT 0         // [256][256] bf16   (W1cat transposed: [n][k])
#define WS_W2T   131072    // [64][256]  bf16   (W2 transposed: [o][h])
#define WS_WDS   163840    // 65 f32 (Wd[64], bd)
#define WS_BIAS1 164096    // [1024][256] f32

__device__ __forceinline__ u16 f2bf_rne(float f){
  union { float f; unsigned u; } v; v.f = f;
  unsigned r = v.u + 0x7fffu + ((v.u >> 16) & 1u);
  return (u16)(r >> 16);
}
// pack two floats' top-16 (trunc-to-bf16): cheap, accuracy headroom is 20x
__device__ __forceinline__ u32 pack_trunc(float a, float b){
  return (__float_as_uint(a) >> 16) | (__float_as_uint(b) & 0xffff0000u);
}
__device__ __forceinline__ int swz(int byte){   // row stride 512B XOR swizzle (16B grain)
  return byte ^ (((byte >> 9) & 7) << 4);
}
__device__ __forceinline__ float sigmoidf(float x){ return 1.f / (1.f + __expf(-x)); }

// barrier that does NOT drain vmcnt — keeps prefetched global->reg loads in flight.
// lgkmcnt(0) guarantees LDS writes visible before the barrier.
__device__ __forceinline__ void barrier_lds(){
  asm volatile("s_waitcnt lgkmcnt(0)" ::: "memory");
  __builtin_amdgcn_s_barrier();
  asm volatile("" ::: "memory");
}

// ---- prep 1: fold weights to bf16, transposed ----
__global__ void prep_weights(const float* __restrict__ W1, const float* __restrict__ W2,
                             const float* __restrict__ Wd, const float* __restrict__ bd,
                             u16* __restrict__ WcatT, u16* __restrict__ W2T,
                             float* __restrict__ WdS){
  int n = blockIdx.x;      // hidden col 0..255
  int k = threadIdx.x;     // feat k 0..255
  float v;
  if (k < 128) v = W1[(128 + k) * NH1 + n] - W1[(256 + k) * NH1 + n];  // (B - C) for keys
  else         v = W1[(384 + (k - 128)) * NH1 + n];                    // D for q*k
  WcatT[n * 256 + k] = f2bf_rne(v);
  if (n < NH2) W2T[n * 256 + k] = f2bf_rne(W2[k * NH2 + n]);
  if (n == 0 && k < NH2) WdS[k] = Wd[k];
  if (n == 0 && k == NH2) WdS[NH2] = bd[0];
}

// ---- prep 2: per-batch layer1 bias = b1 + q @ (W1a + W1c) ----
__global__ void prep_bias(const float* __restrict__ q, const float* __restrict__ W1,
                          const float* __restrict__ b1, float* __restrict__ bias1){
  __shared__ float qsh[DD];
  int b = blockIdx.x, j = threadIdx.x;
  if (j < DD) qsh[j] = q[b * DD + j];
  __syncthreads();
  float acc = b1[j];
  #pragma unroll 8
  for (int d = 0; d < DD; ++d)
    acc += qsh[d] * (W1[d * NH1 + j] + W1[(256 + d) * NH1 + j]);
  bias1[b * NH1 + j] = acc;
}

// ---- main: one block per batch, 4 waves ----
__global__ __launch_bounds__(256, 4)
void seqatt_main(const float* __restrict__ queries, const float* __restrict__ keys,
                 const int* __restrict__ keys_length,
                 const u16* __restrict__ WcatT, const u16* __restrict__ W2Tg,
                 const float* __restrict__ WdS, const float* __restrict__ bias1g,
                 const float* __restrict__ b2g, float* __restrict__ out)
{
  // LDS: 0 A[32][512B] (reused as red f32[256] at end); 16384 h1[32][512B];
  //      32768 scores f32[256]; 33792 bias1 f32[256]; 34816 b2 f32[64];
  //      35072 wd f32[66]; 35336 red4 f32[8]
  __shared__ alignas(16) char smem[35392];
  float* scores = (float*)(smem + 32768);
  float* bias1s = (float*)(smem + 33792);
  float* b2s    = (float*)(smem + 34816);
  float* wds    = (float*)(smem + 35072);
  float* red4   = (float*)(smem + 35336);

  const int b = blockIdx.x;
  const int tid = threadIdx.x;
  const int lane = tid & 63;
  const int wave = tid >> 6;
  const int l15 = lane & 15;
  const int l4  = lane >> 4;
  const int nbase = wave * 64;
  const int r = tid >> 3, seg = tid & 7;   // A-build: 8 threads/row, 16 floats each

  bias1s[tid] = bias1g[b * NH1 + tid];
  if (tid < 64) b2s[tid] = b2g[tid];
  if (tid < 65) wds[tid] = WdS[tid];
  const int klen = keys_length[b];

  // q slice for this thread's seg — stationary in registers (q constant over tiles)
  const float* qp = queries + b * DD + seg * 16;
  float4 qv0 = *(const float4*)(qp + 0);
  float4 qv1 = *(const float4*)(qp + 4);
  float4 qv2 = *(const float4*)(qp + 8);
  float4 qv3 = *(const float4*)(qp + 12);

  // prefetch keys for tile 0
  const float* kbase = keys + (long)b * SLEN * DD + seg * 16;
  float4 kv0, kv1, kv2, kv3;
  {
    const float* p = kbase + (long)r * DD;
    kv0 = *(const float4*)(p + 0); kv1 = *(const float4*)(p + 4);
    kv2 = *(const float4*)(p + 8); kv3 = *(const float4*)(p + 12);
  }
  barrier_lds();

  const f32x4 fz = {0.f, 0.f, 0.f, 0.f};
  const u16* wp  = WcatT + (nbase + l15) * 256 + (l4 << 3);    // GEMM1 B base
  const u16* w2p = W2Tg + l15 * 256 + (l4 << 3);               // GEMM2 B base

  for (int st = 0; st < 8; ++st){
    const int s0 = st * 32;

    // ---- A tile: [k | q*k] as bf16 (trunc), swizzled ----
    {
      int rowbyte = r * 512 + seg * 32;
      uint4 pk;
      pk.x = pack_trunc(kv0.x, kv0.y); pk.y = pack_trunc(kv0.z, kv0.w);
      pk.z = pack_trunc(kv1.x, kv1.y); pk.w = pack_trunc(kv1.z, kv1.w);
      *(uint4*)(smem + swz(rowbyte)) = pk;
      pk.x = pack_trunc(kv2.x, kv2.y); pk.y = pack_trunc(kv2.z, kv2.w);
      pk.z = pack_trunc(kv3.x, kv3.y); pk.w = pack_trunc(kv3.z, kv3.w);
      *(uint4*)(smem + swz(rowbyte + 16)) = pk;
      float4 m0, m1;
      m0.x = kv0.x*qv0.x; m0.y = kv0.y*qv0.y; m0.z = kv0.z*qv0.z; m0.w = kv0.w*qv0.w;
      m1.x = kv1.x*qv1.x; m1.y = kv1.y*qv1.y; m1.z = kv1.z*qv1.z; m1.w = kv1.w*qv1.w;
      pk.x = pack_trunc(m0.x, m0.y); pk.y = pack_trunc(m0.z, m0.w);
      pk.z = pack_trunc(m1.x, m1.y); pk.w = pack_trunc(m1.z, m1.w);
      *(uint4*)(smem + swz(rowbyte + 256)) = pk;
      m0.x = kv2.x*qv2.x; m0.y = kv2.y*qv2.y; m0.z = kv2.z*qv2.z; m0.w = kv2.w*qv2.w;
      m1.x = kv3.x*qv3.x; m1.y = kv3.y*qv3.y; m1.z = kv3.z*qv3.z; m1.w = kv3.w*qv3.w;
      pk.x = pack_trunc(m0.x, m0.y); pk.y = pack_trunc(m0.z, m0.w);
      pk.z = pack_trunc(m1.x, m1.y); pk.w = pack_trunc(m1.z, m1.w);
      *(uint4*)(smem + swz(rowbyte + 256 + 16)) = pk;
    }
    // prefetch next tile's keys (stays in flight across lgkmcnt-only barriers)
    if (st < 7){
      const float* p = kbase + (long)(s0 + 32 + r) * DD;
      kv0 = *(const float4*)(p + 0); kv1 = *(const float4*)(p + 4);
      kv2 = *(const float4*)(p + 8); kv3 = *(const float4*)(p + 12);
    }
    barrier_lds();   // A visible

    // ---- GEMM1: h1_pre = A @ W1cat (per wave: M=32, N=64, K=256), B streamed from L2 ----
    f32x4 acc[2][4];
    #pragma unroll
    for (int mt = 0; mt < 2; ++mt)
      #pragma unroll
      for (int nt = 0; nt < 4; ++nt) acc[mt][nt] = fz;

    bf16x8 bcur[4], bnxt[4];
    #pragma unroll
    for (int nt = 0; nt < 4; ++nt) bcur[nt] = *(const bf16x8*)(wp + nt * 4096);
    #pragma unroll
    for (int ks = 0; ks < 8; ++ks){
      if (ks < 7){
        #pragma unroll
        for (int nt = 0; nt < 4; ++nt)
          bnxt[nt] = *(const bf16x8*)(wp + nt * 4096 + (ks + 1) * 32);
      }
      bf16x8 af[2];
      #pragma unroll
      for (int mt = 0; mt < 2; ++mt)
        af[mt] = *(const bf16x8*)(smem + swz((mt * 16 + l15) * 512 + (ks * 32 + (l4 << 3)) * 2));
      #pragma unroll
      for (int mt = 0; mt < 2; ++mt)
        #pragma unroll
        for (int nt = 0; nt < 4; ++nt)
          acc[mt][nt] = __builtin_amdgcn_mfma_f32_16x16x32_bf16(af[mt], bcur[nt], acc[mt][nt], 0, 0, 0);
      #pragma unroll
      for (int nt = 0; nt < 4; ++nt) bcur[nt] = bnxt[nt];
    }

    // ---- bias + sigmoid -> h1 LDS bf16 (wave writes its own n-columns) ----
    #pragma unroll
    for (int mt = 0; mt < 2; ++mt)
      #pragma unroll
      for (int nt = 0; nt < 4; ++nt){
        int col = nbase + nt * 16 + l15;
        float bia = bias1s[col];
        #pragma unroll
        for (int i = 0; i < 4; ++i){
          int row = mt * 16 + (l4 << 2) + i;
          float h = sigmoidf(acc[mt][nt][i] + bia);
          *(u16*)(smem + swz(16384 + row * 512 + col * 2)) = f2bf_rne(h);
        }
      }
    barrier_lds();   // h1 visible

    // ---- GEMM2 on waves 0/1: 16 rows each, full K=256, no cross-wave reduce ----
    if (wave < 2){
      f32x4 acc2[4];
      #pragma unroll
      for (int nt = 0; nt < 4; ++nt) acc2[nt] = fz;
      bf16x8 wcur[4], wnxt[4];
      #pragma unroll
      for (int nt = 0; nt < 4; ++nt) wcur[nt] = *(const bf16x8*)(w2p + nt * 4096);
      #pragma unroll
      for (int ks = 0; ks < 8; ++ks){
        if (ks < 7){
          #pragma unroll
          for (int nt = 0; nt < 4; ++nt)
            wnxt[nt] = *(const bf16x8*)(w2p + nt * 4096 + (ks + 1) * 32);
        }
        bf16x8 a2 = *(const bf16x8*)(smem + swz(16384 + (wave * 16 + l15) * 512 + (ks * 32 + (l4 << 3)) * 2));
        #pragma unroll
        for (int nt = 0; nt < 4; ++nt)
          acc2[nt] = __builtin_amdgcn_mfma_f32_16x16x32_bf16(a2, wcur[nt], acc2[nt], 0, 0, 0);
        #pragma unroll
        for (int nt = 0; nt < 4; ++nt) wcur[nt] = wnxt[nt];
      }
      // sigmoid + dot(Wd) + reduce over the 16 o-lanes
      float p0 = 0.f, p1 = 0.f, p2 = 0.f, p3 = 0.f;
      #pragma unroll
      for (int nt = 0; nt < 4; ++nt){
        int o = nt * 16 + l15;
        float b2v = b2s[o], wdv = wds[o];
        p0 += sigmoidf(acc2[nt][0] + b2v) * wdv;
        p1 += sigmoidf(acc2[nt][1] + b2v) * wdv;
        p2 += sigmoidf(acc2[nt][2] + b2v) * wdv;
        p3 += sigmoidf(acc2[nt][3] + b2v) * wdv;
      }
      #pragma unroll
      for (int off = 1; off < 16; off <<= 1){
        p0 += __shfl_xor(p0, off);
        p1 += __shfl_xor(p1, off);
        p2 += __shfl_xor(p2, off);
        p3 += __shfl_xor(p3, off);
      }
      if (l15 == 0){
        const float sc = 0.08838834764831845f;  // 1/sqrt(128)
        float bdv = wds[64];
        int sb = s0 + wave * 16 + (l4 << 2);
        scores[sb + 0] = (sb + 0 < klen) ? (p0 + bdv) * sc : -1e30f;
        scores[sb + 1] = (sb + 1 < klen) ? (p1 + bdv) * sc : -1e30f;
        scores[sb + 2] = (sb + 2 < klen) ? (p2 + bdv) * sc : -1e30f;
        scores[sb + 3] = (sb + 3 < klen) ? (p3 + bdv) * sc : -1e30f;
      }
    }
    barrier_lds();   // h1/A reads + scores done before next tile overwrites
  }

  // ---- softmax over S=256 ----
  {
    float v = scores[tid];
    float m = v;
    #pragma unroll
    for (int off = 32; off >= 1; off >>= 1) m = fmaxf(m, __shfl_xor(m, off));
    if (lane == 0) red4[wave] = m;
    __syncthreads();
    float mx = fmaxf(fmaxf(red4[0], red4[1]), fmaxf(red4[2], red4[3]));
    float e = __expf(v - mx);
    float ssum = e;
    #pragma unroll
    for (int off = 32; off >= 1; off >>= 1) ssum += __shfl_xor(ssum, off);
    if (lane == 0) red4[4 + wave] = ssum;
    __syncthreads();
    float tot = red4[4] + red4[5] + red4[6] + red4[7];
    scores[tid] = e / tot;
    __syncthreads();
  }

  // ---- out[b][d] = sum_s w[s] * keys[b][s][d]  (fp32, keys re-read is L2-hit) ----
  {
    float* red = (float*)smem;
    int d = tid & 127, half = tid >> 7;
    const float* kb = keys + ((long)b * SLEN + half * 128) * DD + d;
    float acc = 0.f;
    #pragma unroll 4
    for (int s2 = 0; s2 < 128; ++s2) acc += scores[half * 128 + s2] * kb[s2 * DD];
    red[tid] = acc;
    __syncthreads();
    if (tid < 128) out[b * DD + tid] = red[tid] + red[128 + tid];
  }
}

extern "C" void kernel_launch(void* const* d_in, const int* in_sizes, int n_in,
                              void* d_out, int out_size, void* d_ws, size_t ws_size,
                              hipStream_t stream) {
  const float* queries     = (const float*)d_in[0];
  const float* keys        = (const float*)d_in[1];
  const int*   keys_length = (const int*)d_in[2];
  const float* W1 = (const float*)d_in[3];
  const float* b1 = (const float*)d_in[4];
  const float* W2 = (const float*)d_in[5];
  const float* b2 = (const float*)d_in[6];
  const float* Wd = (const float*)d_in[7];
  const float* bd = (const float*)d_in[8];
  float* out = (float*)d_out;
  char* ws = (char*)d_ws;

  u16*   WcatT = (u16*)(ws + WS_WCATT);
  u16*   W2T   = (u16*)(ws + WS_W2T);
  float* WdS   = (float*)(ws + WS_WDS);
  float* bias1 = (float*)(ws + WS_BIAS1);

  prep_weights<<<dim3(256), dim3(256), 0, stream>>>(W1, W2, Wd, bd, WcatT, W2T, WdS);
  prep_bias<<<dim3(NBATCH), dim3(256), 0, stream>>>(queries, W1, b1, bias1);
  seqatt_main<<<dim3(NBATCH), dim3(256), 0, stream>>>(queries, keys, keys_length,
                                                      WcatT, W2T, WdS, bias1, b2, out);
}